// Round 12
// baseline (256.079 us; speedup 1.0000x reference)
//
#include <hip/hip_runtime.h>
#include <stdint.h>

// CrossAttentionHead: B=8, C=768, S=T=2304, D=512.
// transpose/cvt -> qkv8 (256^2 8-phase BK=64, counted vmcnt, T2 swizzle) ->
// scores8 (same core, exp+store epilogue ONLY) ->
// pv8 (NT=36; denom computed in-kernel via ones-column MFMA; fp32 epilogue).
// Batch->XCD swizzle everywhere. No atomics, no denom buffer.
//
// Round-12: round-9 base; scores' shfl-reduce+atomic epilogue removed;
// denominator = rowsum(P) computed in pv8 by mfma(a, ones) in the four
// A-fresh phases (P1/P3/P5/P7) -> acc_d[8]; every lane holds full rowsum
// for its (mf,fq,r) rows (identical across wc-waves; no reduction needed).
//
// Workspace (ushort elems):
//   Q[0,..) K[9437184,..) Vt[18874368,..)  (each 9,437,184)
//   P@28311552 (42,467,328 elems, 85MB); aliased inside P (dead before P):
//   xs@28311552, xts@42467328, wcat@56623104 (wq|wk|wv, 1536x768),
//   bcat(f32)@ushort 57802752.

typedef __bf16 bf16x8 __attribute__((ext_vector_type(8)));
typedef float f32x4 __attribute__((ext_vector_type(4)));

__device__ __forceinline__ unsigned short f2bf(float f) {
  union { float f; unsigned int u; } c; c.f = f;
  return (unsigned short)((c.u + 0x7fffu + ((c.u >> 16) & 1u)) >> 16); // RNE
}

#define GLOAD(gp, lp)                                                          \
  __builtin_amdgcn_global_load_lds(                                            \
      (const __attribute__((address_space(1))) void*)(gp),                     \
      (__attribute__((address_space(3))) void*)(lp), 16, 0, 0)

// ---- all three weights fp32 -> bf16 into contiguous wcat ----
__global__ __launch_bounds__(256) void convw3_kernel(const float* __restrict__ wq,
                                                     const float* __restrict__ wk,
                                                     const float* __restrict__ wv,
                                                     unsigned short* __restrict__ wcat) {
  int i = (blockIdx.x * 256 + threadIdx.x) * 4;
  const float* src = (i < 393216) ? wq : (i < 786432) ? wk : wv;
  const int off = (i < 393216) ? 0 : (i < 786432) ? 393216 : 786432;
  const float4 v = *reinterpret_cast<const float4*>(src + (i - off));
  wcat[i + 0] = f2bf(v.x); wcat[i + 1] = f2bf(v.y);
  wcat[i + 2] = f2bf(v.z); wcat[i + 3] = f2bf(v.w);
}

// ---- concat bias ----
__global__ __launch_bounds__(256) void init_kernel(const float* __restrict__ bq,
                                                   const float* __restrict__ bk,
                                                   const float* __restrict__ bv,
                                                   float* __restrict__ bcat) {
  int k = blockIdx.x * 256 + threadIdx.x;
  if (k < 1536)
    bcat[k] = (k < 512) ? bq[k] : (k < 1024) ? bk[k - 512] : bv[k - 1024];
}

// ---- x[b][c][s] fp32 -> xs[b][s][c] bf16 (64x64 LDS tiles) ----
__global__ __launch_bounds__(256) void transpose_bf16_kernel(
    const float* __restrict__ x, const float* __restrict__ xt,
    unsigned short* __restrict__ xs, unsigned short* __restrict__ xts) {
  const int S = 2304, C = 768;
  const int z = blockIdx.z;
  const float* src = (z < 8) ? x : xt;
  unsigned short* dst = (z < 8) ? xs : xts;
  const int b = z & 7;
  src += (size_t)b * C * S;
  dst += (size_t)b * S * C;
  __shared__ float tile[64][65];
  const int s0 = blockIdx.x * 64, c0 = blockIdx.y * 64;
  const int ls = threadIdx.x & 63, lr = threadIdx.x >> 6;
#pragma unroll
  for (int i = 0; i < 16; ++i) {
    const int c = lr + i * 4;
    tile[c][ls] = src[(size_t)(c0 + c) * S + s0 + ls];
  }
  __syncthreads();
#pragma unroll
  for (int i = 0; i < 16; ++i) {
    const int s = lr + i * 4;
    dst[(size_t)(s0 + s) * C + c0 + ls] = f2bf(tile[ls][s]);
  }
}

// ================= 8-phase 256x256 GEMM-BT core (BK=64) =================
// LDS regions (16KB each, 128KB total): idx = dbuf*4 + side*2 + half.
// Swizzle (both sides): LDS 16B-slot sl at row r holds global slot sl^(r&7).

__device__ __forceinline__ void stage_half8(
    unsigned short* __restrict__ lds, const unsigned short* __restrict__ gb,
    int ldg, int tK, int side, int h, int tid, int swcol) {
  const int d = tK & 1;
  unsigned short* l0 = lds + (size_t)((d * 4 + side * 2 + h) * 8192);
  const unsigned short* g =
      gb + (size_t)(h * 128 + (tid >> 3)) * ldg + tK * 64 + swcol;
  GLOAD(g, l0 + (size_t)tid * 8);
  GLOAD(g + (size_t)64 * ldg, l0 + (size_t)(tid + 512) * 8);
}

#define RD(baseB, rh, cb)                                        \
  (*reinterpret_cast<const bf16x8*>(                             \
      reinterpret_cast<const char*>(lds) + (baseB) + (rh)*128 + (cb)))

#define PH_READ_A0(ABASE)                              \
  _Pragma("unroll") for (int mf = 0; mf < 4; ++mf) {   \
    a[mf][0] = RD(ABASE, mf * 16 + fr, cb0);           \
    a[mf][1] = RD(ABASE, mf * 16 + fr, cb1);           \
  }
#define PH_READ_A4(ABASE)                              \
  _Pragma("unroll") for (int mf = 0; mf < 4; ++mf) {   \
    a[mf][0] = RD(ABASE, 64 + mf * 16 + fr, cb0);      \
    a[mf][1] = RD(ABASE, 64 + mf * 16 + fr, cb1);      \
  }
#define PH_READ_B01(BBASE)                             \
  _Pragma("unroll") for (int nf = 0; nf < 2; ++nf) {   \
    b01[nf][0] = RD(BBASE, brh + nf * 16, cb0);        \
    b01[nf][1] = RD(BBASE, brh + nf * 16, cb1);        \
  }
#define PH_READ_B23(BBASE)                             \
  _Pragma("unroll") for (int nf = 0; nf < 2; ++nf) {   \
    b23[nf][0] = RD(BBASE, brh + 32 + nf * 16, cb0);   \
    b23[nf][1] = RD(BBASE, brh + 32 + nf * 16, cb1);   \
  }

// DS=1 phases additionally accumulate rowsums: acc_d[MB+mf] += a . ones
#define BARRIER_MFMA(MB, NB, BF, DS)                                  \
  __builtin_amdgcn_s_barrier();                                       \
  asm volatile("s_waitcnt lgkmcnt(0)" ::: "memory");                  \
  __builtin_amdgcn_sched_barrier(0);                                  \
  __builtin_amdgcn_s_setprio(1);                                      \
  _Pragma("unroll") for (int mf = 0; mf < 4; ++mf) {                  \
    acc[MB + mf][NB + 0] = __builtin_amdgcn_mfma_f32_16x16x32_bf16(   \
        a[mf][0], BF[0][0], acc[MB + mf][NB + 0], 0, 0, 0);           \
    acc[MB + mf][NB + 0] = __builtin_amdgcn_mfma_f32_16x16x32_bf16(   \
        a[mf][1], BF[0][1], acc[MB + mf][NB + 0], 0, 0, 0);           \
    acc[MB + mf][NB + 1] = __builtin_amdgcn_mfma_f32_16x16x32_bf16(   \
        a[mf][0], BF[1][0], acc[MB + mf][NB + 1], 0, 0, 0);           \
    acc[MB + mf][NB + 1] = __builtin_amdgcn_mfma_f32_16x16x32_bf16(   \
        a[mf][1], BF[1][1], acc[MB + mf][NB + 1], 0, 0, 0);           \
  }                                                                   \
  if constexpr (DSUM) {                                               \
    if constexpr (DS) {                                               \
      _Pragma("unroll") for (int mf = 0; mf < 4; ++mf) {              \
        accd[MB + mf] = __builtin_amdgcn_mfma_f32_16x16x32_bf16(      \
            a[mf][0], vones, accd[MB + mf], 0, 0, 0);                 \
        accd[MB + mf] = __builtin_amdgcn_mfma_f32_16x16x32_bf16(      \
            a[mf][1], vones, accd[MB + mf], 0, 0, 0);                 \
      }                                                               \
    }                                                                 \
  }                                                                   \
  __builtin_amdgcn_s_setprio(0);                                      \
  __builtin_amdgcn_s_barrier();

template <int NT, bool DSUM>
__device__ __forceinline__ void gemm8_core(
    const unsigned short* __restrict__ Ab, const unsigned short* __restrict__ Bb,
    int lda, int ldb, unsigned short* __restrict__ lds, f32x4 (&acc)[8][4],
    f32x4 (&accd)[8]) {
  const int t = threadIdx.x;
  const int lane = t & 63, wid = t >> 6;
  const int wr = wid >> 2, wc = wid & 3;
  const int fr = lane & 15, fq = lane >> 4;
  const int swm = (fr & 7) << 4;
  const int cb0 = (fq * 16) ^ swm;
  const int cb1 = (64 + fq * 16) ^ swm;
  const int brh = (wc & 1) * 64 + fr;
  const int aB0 = (0 + wr) * 16384, aB1 = (4 + wr) * 16384;
  const int bB0 = (2 + (wc >> 1)) * 16384, bB1 = (6 + (wc >> 1)) * 16384;
  const int swcol = (((t & 7) ^ ((t >> 3) & 7))) * 8;

  bf16x8 a[4][2], b01[2][2], b23[2][2];
  bf16x8 vones;
  {
    unsigned short os = 0x3F80;  // bf16 1.0
#pragma unroll
    for (int j = 0; j < 8; ++j)
      reinterpret_cast<unsigned short*>(&vones)[j] = os;
  }

  // prologue: T0.B0,B1,A0,A1, T1.B0,B1 (12 loads); drain all but last 4
  stage_half8(lds, Bb, ldb, 0, 1, 0, t, swcol);
  stage_half8(lds, Bb, ldb, 0, 1, 1, t, swcol);
  stage_half8(lds, Ab, lda, 0, 0, 0, t, swcol);
  stage_half8(lds, Ab, lda, 0, 0, 1, t, swcol);
  stage_half8(lds, Bb, ldb, 1, 1, 0, t, swcol);
  stage_half8(lds, Bb, ldb, 1, 1, 1, t, swcol);
  asm volatile("s_waitcnt vmcnt(4)" ::: "memory");
  __builtin_amdgcn_s_barrier();

  const int NI = NT / 2;
#pragma unroll 1
  for (int i = 0; i < NI; ++i) {
    const bool more = (i + 1 < NI);
    const int tu1 = 2 * i + 1, tu2 = 2 * i + 2, tu3 = 2 * i + 3;
    // ---- P1: read B01(u)+A03(u); stage T(2i+1).A0 ----
    PH_READ_B01(bB0); PH_READ_A0(aB0);
    stage_half8(lds, Ab, lda, tu1, 0, 0, t, swcol);
    BARRIER_MFMA(0, 0, b01, 1);
    // ---- P2: read B23(u); stage T(2i+1).A1 ----
    PH_READ_B23(bB0);
    stage_half8(lds, Ab, lda, tu1, 0, 1, t, swcol);
    BARRIER_MFMA(0, 2, b23, 0);
    // ---- P3: read A47(u); stage T(2i+2).B0 ----
    PH_READ_A4(aB0);
    if (more) stage_half8(lds, Bb, ldb, tu2, 1, 0, t, swcol);
    BARRIER_MFMA(4, 2, b23, 1);
    // ---- P4: stage T(2i+2).B1; gate tile 2i+1 ----
    if (more) {
      stage_half8(lds, Bb, ldb, tu2, 1, 1, t, swcol);
      asm volatile("s_waitcnt vmcnt(4)" ::: "memory");
    } else {
      asm volatile("s_waitcnt vmcnt(0)" ::: "memory");
    }
    BARRIER_MFMA(4, 0, b01, 0);
    // ---- P5: read B01(v)+A03(v); stage T(2i+2).A0 ----
    PH_READ_B01(bB1); PH_READ_A0(aB1);
    if (more) stage_half8(lds, Ab, lda, tu2, 0, 0, t, swcol);
    BARRIER_MFMA(0, 0, b01, 1);
    // ---- P6: read B23(v); stage T(2i+2).A1 ----
    PH_READ_B23(bB1);
    if (more) stage_half8(lds, Ab, lda, tu2, 0, 1, t, swcol);
    BARRIER_MFMA(0, 2, b23, 0);
    // ---- P7: read A47(v); stage T(2i+3).B0 ----
    PH_READ_A4(aB1);
    if (more) stage_half8(lds, Bb, ldb, tu3, 1, 0, t, swcol);
    BARRIER_MFMA(4, 2, b23, 1);
    // ---- P8: stage T(2i+3).B1; gate tile 2i+2 ----
    if (more) {
      stage_half8(lds, Bb, ldb, tu3, 1, 1, t, swcol);
      asm volatile("s_waitcnt vmcnt(4)" ::: "memory");
    }
    BARRIER_MFMA(4, 0, b01, 0);
  }
}

// ---- fused QKV projection, 8-phase 256^2, K=768 (NT=12) ----
__global__ __launch_bounds__(512) void qkv8_kernel(
    const unsigned short* __restrict__ xs, const unsigned short* __restrict__ xts,
    const unsigned short* __restrict__ wcat, const float* __restrict__ bcat,
    unsigned short* __restrict__ Q, unsigned short* __restrict__ K,
    unsigned short* __restrict__ Vt) {
  extern __shared__ unsigned short lds[];
  const int lin = blockIdx.x + 6 * (blockIdx.y + 9 * blockIdx.z);
  const int b = lin & 7, idx = lin >> 3;       // idx in [0,54)
  const int byp = idx / 6, bxp = idx - byp * 6;
  const int m0 = byp * 256, n0 = bxp * 256;
  const int seg = n0 >> 9;
  const unsigned short* Ab =
      ((seg == 0) ? xs : xts) + (size_t)b * 2304 * 768 + (size_t)m0 * 768;
  const unsigned short* Bb = wcat + (size_t)n0 * 768;
  f32x4 acc[8][4] = {};
  f32x4 accd[8] = {};
  gemm8_core<12, false>(Ab, Bb, 768, 768, lds, acc, accd);

  const int t = threadIdx.x;
  const int lane = t & 63, wid = t >> 6;
  const int wr = wid >> 2, wc = wid & 3;
  const int fr = lane & 15, fq = lane >> 4;
  if (seg < 2) {
    unsigned short* Cp = ((seg == 0) ? Q : K) + (size_t)b * 2304 * 512;
#pragma unroll
    for (int nf = 0; nf < 4; ++nf) {
      const int ng = n0 + wc * 64 + nf * 16 + fr;
      const float bj = bcat[ng];
      const int col = ng - seg * 512;
#pragma unroll
      for (int mf = 0; mf < 8; ++mf) {
        const int rbase = m0 + wr * 128 + mf * 16 + fq * 4;
#pragma unroll
        for (int r = 0; r < 4; ++r)
          Cp[(size_t)(rbase + r) * 512 + col] = f2bf(acc[mf][nf][r] + bj);
      }
    }
  } else {
    unsigned short* Cp = Vt + (size_t)b * 512 * 2304;
#pragma unroll
    for (int nf = 0; nf < 4; ++nf) {
      const int ng = n0 + wc * 64 + nf * 16 + fr;
      const float bj = bcat[ng];
      const int d = ng - 1024;
#pragma unroll
      for (int mf = 0; mf < 8; ++mf) {
        const int tb = m0 + wr * 128 + mf * 16 + fq * 4;
        ushort4 pk;
        pk.x = f2bf(acc[mf][nf][0] + bj);
        pk.y = f2bf(acc[mf][nf][1] + bj);
        pk.z = f2bf(acc[mf][nf][2] + bj);
        pk.w = f2bf(acc[mf][nf][3] + bj);
        *reinterpret_cast<ushort4*>(&Cp[(size_t)d * 2304 + tb]) = pk;
      }
    }
  }
}

// ---- scores, 8-phase 256^2, K=512 (NT=8): P = exp(QK^T*sc - 4) ----
// Epilogue is exp+store ONLY (no reduce, no atomics).
__global__ __launch_bounds__(512) void scores8_kernel(
    const unsigned short* __restrict__ Qm, const unsigned short* __restrict__ Km,
    unsigned short* __restrict__ P) {
  extern __shared__ unsigned short lds[];
  const int lin = blockIdx.x + 9 * (blockIdx.y + 9 * blockIdx.z);
  const int b = lin & 7, idx = lin >> 3;       // idx in [0,81)
  const int bxp = idx / 9, byp = idx - bxp * 9;
  const int m0 = byp * 256, n0 = bxp * 256;
  const unsigned short* Ab = Qm + (size_t)b * 2304 * 512 + (size_t)m0 * 512;
  const unsigned short* Bb = Km + (size_t)b * 2304 * 512 + (size_t)n0 * 512;
  f32x4 acc[8][4] = {};
  f32x4 accd[8] = {};
  gemm8_core<8, false>(Ab, Bb, 512, 512, lds, acc, accd);

  const int t = threadIdx.x;
  const int lane = t & 63, wid = t >> 6;
  const int wr = wid >> 2, wc = wid & 3;
  const int fr = lane & 15, fq = lane >> 4;
  unsigned short* Pp = P + (size_t)b * 2304 * 2304;
  const float SC = 0.044194173824159216f;
#pragma unroll
  for (int mf = 0; mf < 8; ++mf) {
    const int rbase = m0 + wr * 128 + mf * 16 + fq * 4;
#pragma unroll
    for (int nf = 0; nf < 4; ++nf) {
      const int col = n0 + wc * 64 + nf * 16 + fr;
#pragma unroll
      for (int r = 0; r < 4; ++r)
        Pp[(size_t)(rbase + r) * 2304 + col] =
            f2bf(__expf(acc[mf][nf][r] * SC - 4.0f));
    }
  }
}

// ---- PV, 8-phase 256^2, K=2304 (NT=36, DSUM): out = (P@Vt^T)/rowsum(P) ----
__global__ __launch_bounds__(512) void pv8_kernel(
    const unsigned short* __restrict__ P, const unsigned short* __restrict__ Vt,
    float* __restrict__ Out) {
  extern __shared__ unsigned short lds[];
  const int lin = blockIdx.x + 2 * (blockIdx.y + 9 * blockIdx.z);
  const int b = lin & 7, idx = lin >> 3;       // idx in [0,18)
  const int byp = idx >> 1, bxp = idx & 1;
  const int m0 = byp * 256, n0 = bxp * 256;
  const unsigned short* Ab = P + (size_t)b * 2304 * 2304 + (size_t)m0 * 2304;
  const unsigned short* Bb = Vt + (size_t)b * 512 * 2304 + (size_t)n0 * 2304;
  f32x4 acc[8][4] = {};
  f32x4 accd[8] = {};
  gemm8_core<36, true>(Ab, Bb, 2304, 2304, lds, acc, accd);

  const int t = threadIdx.x;
  const int lane = t & 63, wid = t >> 6;
  const int wr = wid >> 2, wc = wid & 3;
  const int fr = lane & 15, fq = lane >> 4;
  float* Cp = Out + (size_t)b * 2304 * 512;
#pragma unroll
  for (int mf = 0; mf < 8; ++mf) {
    const int rbase = m0 + wr * 128 + mf * 16 + fq * 4;
#pragma unroll
    for (int r = 0; r < 4; ++r) {
      const float inv = 1.0f / accd[mf][r];
#pragma unroll
      for (int nf = 0; nf < 4; ++nf) {
        const int col = n0 + wc * 64 + nf * 16 + fr;
        Cp[(size_t)(rbase + r) * 512 + col] = acc[mf][nf][r] * inv;
      }
    }
  }
}

extern "C" void kernel_launch(void* const* d_in, const int* in_sizes, int n_in,
                              void* d_out, int out_size, void* d_ws, size_t ws_size,
                              hipStream_t stream) {
  const float* x  = (const float*)d_in[0];
  const float* xt = (const float*)d_in[1];
  const float* wq = (const float*)d_in[2];
  const float* bq = (const float*)d_in[3];
  const float* wk = (const float*)d_in[4];
  const float* bk = (const float*)d_in[5];
  const float* wv = (const float*)d_in[6];
  const float* bv = (const float*)d_in[7];
  float* out = (float*)d_out;
  unsigned short* ws = (unsigned short*)d_ws;

  unsigned short* Q    = ws;
  unsigned short* Kb   = ws + 9437184;
  unsigned short* Vt   = ws + 18874368;
  unsigned short* P    = ws + 28311552;   // 85MB region
  unsigned short* xs   = ws + 28311552;   // aliases P (dead before P written)
  unsigned short* xts  = ws + 42467328;
  unsigned short* wcat = ws + 56623104;   // wq|wk|wv contiguous (1536x768)
  float* bcat  = (float*)(ws + 57802752); // 1536 f32 (inside P region, dead early)

  static int attr_set = 0;
  if (!attr_set) {
    hipFuncSetAttribute((const void*)qkv8_kernel,
                        hipFuncAttributeMaxDynamicSharedMemorySize, 131072);
    hipFuncSetAttribute((const void*)scores8_kernel,
                        hipFuncAttributeMaxDynamicSharedMemorySize, 131072);
    hipFuncSetAttribute((const void*)pv8_kernel,
                        hipFuncAttributeMaxDynamicSharedMemorySize, 131072);
    attr_set = 1;
  }

  convw3_kernel<<<1152, 256, 0, stream>>>(wq, wk, wv, wcat);
  init_kernel<<<6, 256, 0, stream>>>(bq, bk, bv, bcat);
  transpose_bf16_kernel<<<dim3(36, 12, 16), 256, 0, stream>>>(x, xt, xs, xts);

  // fused Q|K|V projection (8-phase 256^2)
  qkv8_kernel<<<dim3(6, 9, 8), 512, 131072, stream>>>(xs, xts, wcat, bcat, Q, Kb, Vt);

  // P = exp(Q K^T / sqrt(D) - 4)
  scores8_kernel<<<dim3(9, 9, 8), 512, 131072, stream>>>(Q, Kb, P);

  // out = (P @ V) / rowsum(P)  (denominator via ones-MFMA inside)
  pv8_kernel<<<dim3(2, 9, 8), 512, 131072, stream>>>(P, Vt, out);
}

// Round 13
// 222.034 us; speedup vs baseline: 1.1533x; 1.1533x over previous
//
#include <hip/hip_runtime.h>
#include <stdint.h>

// CrossAttentionHead: B=8, C=768, S=T=2304, D=512.
// transpose/cvt -> qkv8 (256^2 8-phase BK=64, counted vmcnt, T2 swizzle) ->
// scores8 (same core, exp+store only) -> rowsum (denom[row]=sum P, L3-BW) ->
// pv8 (round-9 core, 1/denom fp32 epilogue). Batch->XCD swizzle everywhere.
//
// Round-13: round-12's ones-MFMA denom reverted (pv8 50->128us: accd chains
// serialize the MFMA clusters + VGPR/occupancy loss). scores8 keeps the
// epilogue-free form (94->~59us, the reduce+atomic cost ~35us). Denominator
// now a dedicated memory-bound rowsum kernel (P is L3-resident, ~15-20us).
//
// Workspace (ushort elems):
//   Q[0,..) K[9437184,..) Vt[18874368,..)  (each 9,437,184)
//   P@28311552 (42,467,328 elems, 85MB); aliased inside P (dead before P):
//   xs@28311552, xts@42467328, wcat@56623104 (wq|wk|wv, 1536x768),
//   bcat(f32)@ushort 57802752; denom(f32,18432)@ushort 70778880.

typedef __bf16 bf16x8 __attribute__((ext_vector_type(8)));
typedef float f32x4 __attribute__((ext_vector_type(4)));

__device__ __forceinline__ unsigned short f2bf(float f) {
  union { float f; unsigned int u; } c; c.f = f;
  return (unsigned short)((c.u + 0x7fffu + ((c.u >> 16) & 1u)) >> 16); // RNE
}
__device__ __forceinline__ float bf2f(unsigned short h) {
  union { unsigned int u; float f; } c; c.u = ((unsigned int)h) << 16;
  return c.f;
}

#define GLOAD(gp, lp)                                                          \
  __builtin_amdgcn_global_load_lds(                                            \
      (const __attribute__((address_space(1))) void*)(gp),                     \
      (__attribute__((address_space(3))) void*)(lp), 16, 0, 0)

// ---- all three weights fp32 -> bf16 into contiguous wcat ----
__global__ __launch_bounds__(256) void convw3_kernel(const float* __restrict__ wq,
                                                     const float* __restrict__ wk,
                                                     const float* __restrict__ wv,
                                                     unsigned short* __restrict__ wcat) {
  int i = (blockIdx.x * 256 + threadIdx.x) * 4;
  const float* src = (i < 393216) ? wq : (i < 786432) ? wk : wv;
  const int off = (i < 393216) ? 0 : (i < 786432) ? 393216 : 786432;
  const float4 v = *reinterpret_cast<const float4*>(src + (i - off));
  wcat[i + 0] = f2bf(v.x); wcat[i + 1] = f2bf(v.y);
  wcat[i + 2] = f2bf(v.z); wcat[i + 3] = f2bf(v.w);
}

// ---- concat bias ----
__global__ __launch_bounds__(256) void init_kernel(const float* __restrict__ bq,
                                                   const float* __restrict__ bk,
                                                   const float* __restrict__ bv,
                                                   float* __restrict__ bcat) {
  int k = blockIdx.x * 256 + threadIdx.x;
  if (k < 1536)
    bcat[k] = (k < 512) ? bq[k] : (k < 1024) ? bk[k - 512] : bv[k - 1024];
}

// ---- x[b][c][s] fp32 -> xs[b][s][c] bf16 (64x64 LDS tiles) ----
__global__ __launch_bounds__(256) void transpose_bf16_kernel(
    const float* __restrict__ x, const float* __restrict__ xt,
    unsigned short* __restrict__ xs, unsigned short* __restrict__ xts) {
  const int S = 2304, C = 768;
  const int z = blockIdx.z;
  const float* src = (z < 8) ? x : xt;
  unsigned short* dst = (z < 8) ? xs : xts;
  const int b = z & 7;
  src += (size_t)b * C * S;
  dst += (size_t)b * S * C;
  __shared__ float tile[64][65];
  const int s0 = blockIdx.x * 64, c0 = blockIdx.y * 64;
  const int ls = threadIdx.x & 63, lr = threadIdx.x >> 6;
#pragma unroll
  for (int i = 0; i < 16; ++i) {
    const int c = lr + i * 4;
    tile[c][ls] = src[(size_t)(c0 + c) * S + s0 + ls];
  }
  __syncthreads();
#pragma unroll
  for (int i = 0; i < 16; ++i) {
    const int s = lr + i * 4;
    dst[(size_t)(s0 + s) * C + c0 + ls] = f2bf(tile[ls][s]);
  }
}

// ================= 8-phase 256x256 GEMM-BT core (BK=64) =================
// LDS regions (16KB each, 128KB total): idx = dbuf*4 + side*2 + half.
// Swizzle (both sides): LDS 16B-slot sl at row r holds global slot sl^(r&7).

__device__ __forceinline__ void stage_half8(
    unsigned short* __restrict__ lds, const unsigned short* __restrict__ gb,
    int ldg, int tK, int side, int h, int tid, int swcol) {
  const int d = tK & 1;
  unsigned short* l0 = lds + (size_t)((d * 4 + side * 2 + h) * 8192);
  const unsigned short* g =
      gb + (size_t)(h * 128 + (tid >> 3)) * ldg + tK * 64 + swcol;
  GLOAD(g, l0 + (size_t)tid * 8);
  GLOAD(g + (size_t)64 * ldg, l0 + (size_t)(tid + 512) * 8);
}

#define RD(baseB, rh, cb)                                        \
  (*reinterpret_cast<const bf16x8*>(                             \
      reinterpret_cast<const char*>(lds) + (baseB) + (rh)*128 + (cb)))

#define PH_READ_A0(ABASE)                              \
  _Pragma("unroll") for (int mf = 0; mf < 4; ++mf) {   \
    a[mf][0] = RD(ABASE, mf * 16 + fr, cb0);           \
    a[mf][1] = RD(ABASE, mf * 16 + fr, cb1);           \
  }
#define PH_READ_A4(ABASE)                              \
  _Pragma("unroll") for (int mf = 0; mf < 4; ++mf) {   \
    a[mf][0] = RD(ABASE, 64 + mf * 16 + fr, cb0);      \
    a[mf][1] = RD(ABASE, 64 + mf * 16 + fr, cb1);      \
  }
#define PH_READ_B01(BBASE)                             \
  _Pragma("unroll") for (int nf = 0; nf < 2; ++nf) {   \
    b01[nf][0] = RD(BBASE, brh + nf * 16, cb0);        \
    b01[nf][1] = RD(BBASE, brh + nf * 16, cb1);        \
  }
#define PH_READ_B23(BBASE)                             \
  _Pragma("unroll") for (int nf = 0; nf < 2; ++nf) {   \
    b23[nf][0] = RD(BBASE, brh + 32 + nf * 16, cb0);   \
    b23[nf][1] = RD(BBASE, brh + 32 + nf * 16, cb1);   \
  }

#define BARRIER_MFMA(MB, NB, BF)                                      \
  __builtin_amdgcn_s_barrier();                                       \
  asm volatile("s_waitcnt lgkmcnt(0)" ::: "memory");                  \
  __builtin_amdgcn_sched_barrier(0);                                  \
  __builtin_amdgcn_s_setprio(1);                                      \
  _Pragma("unroll") for (int mf = 0; mf < 4; ++mf) {                  \
    acc[MB + mf][NB + 0] = __builtin_amdgcn_mfma_f32_16x16x32_bf16(   \
        a[mf][0], BF[0][0], acc[MB + mf][NB + 0], 0, 0, 0);           \
    acc[MB + mf][NB + 0] = __builtin_amdgcn_mfma_f32_16x16x32_bf16(   \
        a[mf][1], BF[0][1], acc[MB + mf][NB + 0], 0, 0, 0);           \
    acc[MB + mf][NB + 1] = __builtin_amdgcn_mfma_f32_16x16x32_bf16(   \
        a[mf][0], BF[1][0], acc[MB + mf][NB + 1], 0, 0, 0);           \
    acc[MB + mf][NB + 1] = __builtin_amdgcn_mfma_f32_16x16x32_bf16(   \
        a[mf][1], BF[1][1], acc[MB + mf][NB + 1], 0, 0, 0);           \
  }                                                                   \
  __builtin_amdgcn_s_setprio(0);                                      \
  __builtin_amdgcn_s_barrier();

template <int NT>
__device__ __forceinline__ void gemm8_core(
    const unsigned short* __restrict__ Ab, const unsigned short* __restrict__ Bb,
    int lda, int ldb, unsigned short* __restrict__ lds, f32x4 (&acc)[8][4]) {
  const int t = threadIdx.x;
  const int lane = t & 63, wid = t >> 6;
  const int wr = wid >> 2, wc = wid & 3;
  const int fr = lane & 15, fq = lane >> 4;
  const int swm = (fr & 7) << 4;
  const int cb0 = (fq * 16) ^ swm;
  const int cb1 = (64 + fq * 16) ^ swm;
  const int brh = (wc & 1) * 64 + fr;
  const int aB0 = (0 + wr) * 16384, aB1 = (4 + wr) * 16384;
  const int bB0 = (2 + (wc >> 1)) * 16384, bB1 = (6 + (wc >> 1)) * 16384;
  const int swcol = (((t & 7) ^ ((t >> 3) & 7))) * 8;

  bf16x8 a[4][2], b01[2][2], b23[2][2];

  // prologue: T0.B0,B1,A0,A1, T1.B0,B1 (12 loads); drain all but last 4
  stage_half8(lds, Bb, ldb, 0, 1, 0, t, swcol);
  stage_half8(lds, Bb, ldb, 0, 1, 1, t, swcol);
  stage_half8(lds, Ab, lda, 0, 0, 0, t, swcol);
  stage_half8(lds, Ab, lda, 0, 0, 1, t, swcol);
  stage_half8(lds, Bb, ldb, 1, 1, 0, t, swcol);
  stage_half8(lds, Bb, ldb, 1, 1, 1, t, swcol);
  asm volatile("s_waitcnt vmcnt(4)" ::: "memory");
  __builtin_amdgcn_s_barrier();

  const int NI = NT / 2;
#pragma unroll 1
  for (int i = 0; i < NI; ++i) {
    const bool more = (i + 1 < NI);
    const int tu1 = 2 * i + 1, tu2 = 2 * i + 2, tu3 = 2 * i + 3;
    // ---- P1: read B01(u)+A03(u); stage T(2i+1).A0 ----
    PH_READ_B01(bB0); PH_READ_A0(aB0);
    stage_half8(lds, Ab, lda, tu1, 0, 0, t, swcol);
    BARRIER_MFMA(0, 0, b01);
    // ---- P2: read B23(u); stage T(2i+1).A1 ----
    PH_READ_B23(bB0);
    stage_half8(lds, Ab, lda, tu1, 0, 1, t, swcol);
    BARRIER_MFMA(0, 2, b23);
    // ---- P3: read A47(u); stage T(2i+2).B0 ----
    PH_READ_A4(aB0);
    if (more) stage_half8(lds, Bb, ldb, tu2, 1, 0, t, swcol);
    BARRIER_MFMA(4, 2, b23);
    // ---- P4: stage T(2i+2).B1; gate tile 2i+1 ----
    if (more) {
      stage_half8(lds, Bb, ldb, tu2, 1, 1, t, swcol);
      asm volatile("s_waitcnt vmcnt(4)" ::: "memory");
    } else {
      asm volatile("s_waitcnt vmcnt(0)" ::: "memory");
    }
    BARRIER_MFMA(4, 0, b01);
    // ---- P5: read B01(v)+A03(v); stage T(2i+2).A0 ----
    PH_READ_B01(bB1); PH_READ_A0(aB1);
    if (more) stage_half8(lds, Ab, lda, tu2, 0, 0, t, swcol);
    BARRIER_MFMA(0, 0, b01);
    // ---- P6: read B23(v); stage T(2i+2).A1 ----
    PH_READ_B23(bB1);
    if (more) stage_half8(lds, Ab, lda, tu2, 0, 1, t, swcol);
    BARRIER_MFMA(0, 2, b23);
    // ---- P7: read A47(v); stage T(2i+3).B0 ----
    PH_READ_A4(aB1);
    if (more) stage_half8(lds, Bb, ldb, tu3, 1, 0, t, swcol);
    BARRIER_MFMA(4, 2, b23);
    // ---- P8: stage T(2i+3).B1; gate tile 2i+2 ----
    if (more) {
      stage_half8(lds, Bb, ldb, tu3, 1, 1, t, swcol);
      asm volatile("s_waitcnt vmcnt(4)" ::: "memory");
    }
    BARRIER_MFMA(4, 0, b01);
  }
}

// ---- fused QKV projection, 8-phase 256^2, K=768 (NT=12) ----
__global__ __launch_bounds__(512) void qkv8_kernel(
    const unsigned short* __restrict__ xs, const unsigned short* __restrict__ xts,
    const unsigned short* __restrict__ wcat, const float* __restrict__ bcat,
    unsigned short* __restrict__ Q, unsigned short* __restrict__ K,
    unsigned short* __restrict__ Vt) {
  extern __shared__ unsigned short lds[];
  const int lin = blockIdx.x + 6 * (blockIdx.y + 9 * blockIdx.z);
  const int b = lin & 7, idx = lin >> 3;       // idx in [0,54)
  const int byp = idx / 6, bxp = idx - byp * 6;
  const int m0 = byp * 256, n0 = bxp * 256;
  const int seg = n0 >> 9;
  const unsigned short* Ab =
      ((seg == 0) ? xs : xts) + (size_t)b * 2304 * 768 + (size_t)m0 * 768;
  const unsigned short* Bb = wcat + (size_t)n0 * 768;
  f32x4 acc[8][4] = {};
  gemm8_core<12>(Ab, Bb, 768, 768, lds, acc);

  const int t = threadIdx.x;
  const int lane = t & 63, wid = t >> 6;
  const int wr = wid >> 2, wc = wid & 3;
  const int fr = lane & 15, fq = lane >> 4;
  if (seg < 2) {
    unsigned short* Cp = ((seg == 0) ? Q : K) + (size_t)b * 2304 * 512;
#pragma unroll
    for (int nf = 0; nf < 4; ++nf) {
      const int ng = n0 + wc * 64 + nf * 16 + fr;
      const float bj = bcat[ng];
      const int col = ng - seg * 512;
#pragma unroll
      for (int mf = 0; mf < 8; ++mf) {
        const int rbase = m0 + wr * 128 + mf * 16 + fq * 4;
#pragma unroll
        for (int r = 0; r < 4; ++r)
          Cp[(size_t)(rbase + r) * 512 + col] = f2bf(acc[mf][nf][r] + bj);
      }
    }
  } else {
    unsigned short* Cp = Vt + (size_t)b * 512 * 2304;
#pragma unroll
    for (int nf = 0; nf < 4; ++nf) {
      const int ng = n0 + wc * 64 + nf * 16 + fr;
      const float bj = bcat[ng];
      const int d = ng - 1024;
#pragma unroll
      for (int mf = 0; mf < 8; ++mf) {
        const int tb = m0 + wr * 128 + mf * 16 + fq * 4;
        ushort4 pk;
        pk.x = f2bf(acc[mf][nf][0] + bj);
        pk.y = f2bf(acc[mf][nf][1] + bj);
        pk.z = f2bf(acc[mf][nf][2] + bj);
        pk.w = f2bf(acc[mf][nf][3] + bj);
        *reinterpret_cast<ushort4*>(&Cp[(size_t)d * 2304 + tb]) = pk;
      }
    }
  }
}

// ---- scores, 8-phase 256^2, K=512 (NT=8): P = exp(QK^T*sc - 4) ----
// Epilogue: exp+store ONLY.
__global__ __launch_bounds__(512) void scores8_kernel(
    const unsigned short* __restrict__ Qm, const unsigned short* __restrict__ Km,
    unsigned short* __restrict__ P) {
  extern __shared__ unsigned short lds[];
  const int lin = blockIdx.x + 9 * (blockIdx.y + 9 * blockIdx.z);
  const int b = lin & 7, idx = lin >> 3;       // idx in [0,81)
  const int bxp = idx / 9, byp = idx - bxp * 9;
  const int m0 = byp * 256, n0 = bxp * 256;
  const unsigned short* Ab = Qm + (size_t)b * 2304 * 512 + (size_t)m0 * 512;
  const unsigned short* Bb = Km + (size_t)b * 2304 * 512 + (size_t)n0 * 512;
  f32x4 acc[8][4] = {};
  gemm8_core<8>(Ab, Bb, 512, 512, lds, acc);

  const int t = threadIdx.x;
  const int lane = t & 63, wid = t >> 6;
  const int wr = wid >> 2, wc = wid & 3;
  const int fr = lane & 15, fq = lane >> 4;
  unsigned short* Pp = P + (size_t)b * 2304 * 2304;
  const float SC = 0.044194173824159216f;
#pragma unroll
  for (int mf = 0; mf < 8; ++mf) {
    const int rbase = m0 + wr * 128 + mf * 16 + fq * 4;
#pragma unroll
    for (int nf = 0; nf < 4; ++nf) {
      const int col = n0 + wc * 64 + nf * 16 + fr;
#pragma unroll
      for (int r = 0; r < 4; ++r)
        Pp[(size_t)(rbase + r) * 2304 + col] =
            f2bf(__expf(acc[mf][nf][r] * SC - 4.0f));
    }
  }
}

// ---- rowsum: denom[r] = sum_t P[r][t]; one 32-lane group per row ----
// P is L3-resident (just written). 8 rows/block, coalesced 16B chunks,
// shfl reduce within the 32-lane group, direct store (no atomics).
__global__ __launch_bounds__(256) void rowsum_kernel(
    const unsigned short* __restrict__ P, float* __restrict__ denom) {
  const int t = threadIdx.x;
  const int row = blockIdx.x * 8 + (t >> 5);
  const int lane = t & 31;
  const unsigned short* p = P + (size_t)row * 2304;
  float s = 0.f;
#pragma unroll
  for (int it = 0; it < 9; ++it) {
    const int e0 = (it * 32 + lane) * 8;  // 288 chunks of 8 bf16 per row
    const ushort4 v0 = *reinterpret_cast<const ushort4*>(p + e0);
    const ushort4 v1 = *reinterpret_cast<const ushort4*>(p + e0 + 4);
    s += bf2f(v0.x) + bf2f(v0.y) + bf2f(v0.z) + bf2f(v0.w) +
         bf2f(v1.x) + bf2f(v1.y) + bf2f(v1.z) + bf2f(v1.w);
  }
#pragma unroll
  for (int o = 16; o >= 1; o >>= 1) s += __shfl_xor(s, o, 32);
  if (lane == 0) denom[row] = s;
}

// ---- PV, 8-phase 256^2, K=2304 (NT=36): out = (P @ Vt^T)/denom, fp32 ----
__global__ __launch_bounds__(512) void pv8_kernel(
    const unsigned short* __restrict__ P, const unsigned short* __restrict__ Vt,
    const float* __restrict__ denom, float* __restrict__ Out) {
  extern __shared__ unsigned short lds[];
  const int lin = blockIdx.x + 2 * (blockIdx.y + 9 * blockIdx.z);
  const int b = lin & 7, idx = lin >> 3;       // idx in [0,18)
  const int byp = idx >> 1, bxp = idx & 1;
  const int m0 = byp * 256, n0 = bxp * 256;
  const unsigned short* Ab = P + (size_t)b * 2304 * 2304 + (size_t)m0 * 2304;
  const unsigned short* Bb = Vt + (size_t)b * 512 * 2304 + (size_t)n0 * 2304;
  f32x4 acc[8][4] = {};
  gemm8_core<36>(Ab, Bb, 2304, 2304, lds, acc);

  const int t = threadIdx.x;
  const int lane = t & 63, wid = t >> 6;
  const int wr = wid >> 2, wc = wid & 3;
  const int fr = lane & 15, fq = lane >> 4;
  float* Cp = Out + (size_t)b * 2304 * 512;
  const float* dn = denom + (size_t)b * 2304;
#pragma unroll
  for (int mf = 0; mf < 8; ++mf) {
    const int rbase = m0 + wr * 128 + mf * 16 + fq * 4;
#pragma unroll
    for (int r = 0; r < 4; ++r) {
      const float inv = 1.0f / dn[rbase + r];
#pragma unroll
      for (int nf = 0; nf < 4; ++nf) {
        const int col = n0 + wc * 64 + nf * 16 + fr;
        Cp[(size_t)(rbase + r) * 512 + col] = acc[mf][nf][r] * inv;
      }
    }
  }
}

extern "C" void kernel_launch(void* const* d_in, const int* in_sizes, int n_in,
                              void* d_out, int out_size, void* d_ws, size_t ws_size,
                              hipStream_t stream) {
  const float* x  = (const float*)d_in[0];
  const float* xt = (const float*)d_in[1];
  const float* wq = (const float*)d_in[2];
  const float* bq = (const float*)d_in[3];
  const float* wk = (const float*)d_in[4];
  const float* bk = (const float*)d_in[5];
  const float* wv = (const float*)d_in[6];
  const float* bv = (const float*)d_in[7];
  float* out = (float*)d_out;
  unsigned short* ws = (unsigned short*)d_ws;

  unsigned short* Q    = ws;
  unsigned short* Kb   = ws + 9437184;
  unsigned short* Vt   = ws + 18874368;
  unsigned short* P    = ws + 28311552;   // 85MB region
  unsigned short* xs   = ws + 28311552;   // aliases P (dead before P written)
  unsigned short* xts  = ws + 42467328;
  unsigned short* wcat = ws + 56623104;   // wq|wk|wv contiguous (1536x768)
  float* bcat  = (float*)(ws + 57802752); // 1536 f32 (inside P region, dead early)
  float* denom = (float*)(ws + 70778880); // 18432 f32, after P

  static int attr_set = 0;
  if (!attr_set) {
    hipFuncSetAttribute((const void*)qkv8_kernel,
                        hipFuncAttributeMaxDynamicSharedMemorySize, 131072);
    hipFuncSetAttribute((const void*)scores8_kernel,
                        hipFuncAttributeMaxDynamicSharedMemorySize, 131072);
    hipFuncSetAttribute((const void*)pv8_kernel,
                        hipFuncAttributeMaxDynamicSharedMemorySize, 131072);
    attr_set = 1;
  }

  convw3_kernel<<<1152, 256, 0, stream>>>(wq, wk, wv, wcat);
  init_kernel<<<6, 256, 0, stream>>>(bq, bk, bv, bcat);
  transpose_bf16_kernel<<<dim3(36, 12, 16), 256, 0, stream>>>(x, xt, xs, xts);

  // fused Q|K|V projection (8-phase 256^2)
  qkv8_kernel<<<dim3(6, 9, 8), 512, 131072, stream>>>(xs, xts, wcat, bcat, Q, Kb, Vt);

  // P = exp(Q K^T / sqrt(D) - 4)
  scores8_kernel<<<dim3(9, 9, 8), 512, 131072, stream>>>(Q, Kb, P);

  // denom[row] = sum_t P (memory-bound, L3-resident P, no atomics)
  rowsum_kernel<<<2304, 256, 0, stream>>>(P, denom);

  // out = (P @ V) / denom[row]
  pv8_kernel<<<dim3(2, 9, 8), 512, 131072, stream>>>(P, Vt, denom, out);
}

// Round 14
// 219.775 us; speedup vs baseline: 1.1652x; 1.0103x over previous
//
#include <hip/hip_runtime.h>
#include <stdint.h>

// CrossAttentionHead: B=8, C=768, S=T=2304, D=512.
// transpose/cvt -> qkv8 (256^2 8-phase BK=64, counted vmcnt, T2 swizzle) ->
// scores8 (same core; epilogue: exp+store + LDS-combined per-slab row
// partials -> psum, NO atomics) -> combine (denom = sum of 9 partials) ->
// pv8 (round-9 core, 1/denom fp32 epilogue). Batch->XCD swizzle everywhere.
//
// Round-14: round-13's rowsum kernel (85MB P re-read) replaced by in-scores
// psum partials (663KB) + tiny combine. Atomic-free: fr-shfl reduce ->
// cross-wave combine via 4KB of post-loop LDS -> one plain store per row.
//
// Workspace (ushort elems):
//   Q[0,..) K[9437184,..) Vt[18874368,..)  (each 9,437,184)
//   P@28311552 (42,467,328 elems, 85MB); aliased inside P (dead before P):
//   xs@28311552, xts@42467328, wcat@56623104 (wq|wk|wv, 1536x768),
//   bcat(f32)@ushort 57802752; denom(f32,18432)@ushort 70778880;
//   psum(f32, 8*2304*9=165888)@ushort 70815744 (end 142,295,040 B).

typedef __bf16 bf16x8 __attribute__((ext_vector_type(8)));
typedef float f32x4 __attribute__((ext_vector_type(4)));

__device__ __forceinline__ unsigned short f2bf(float f) {
  union { float f; unsigned int u; } c; c.f = f;
  return (unsigned short)((c.u + 0x7fffu + ((c.u >> 16) & 1u)) >> 16); // RNE
}

#define GLOAD(gp, lp)                                                          \
  __builtin_amdgcn_global_load_lds(                                            \
      (const __attribute__((address_space(1))) void*)(gp),                     \
      (__attribute__((address_space(3))) void*)(lp), 16, 0, 0)

// ---- all three weights fp32 -> bf16 into contiguous wcat ----
__global__ __launch_bounds__(256) void convw3_kernel(const float* __restrict__ wq,
                                                     const float* __restrict__ wk,
                                                     const float* __restrict__ wv,
                                                     unsigned short* __restrict__ wcat) {
  int i = (blockIdx.x * 256 + threadIdx.x) * 4;
  const float* src = (i < 393216) ? wq : (i < 786432) ? wk : wv;
  const int off = (i < 393216) ? 0 : (i < 786432) ? 393216 : 786432;
  const float4 v = *reinterpret_cast<const float4*>(src + (i - off));
  wcat[i + 0] = f2bf(v.x); wcat[i + 1] = f2bf(v.y);
  wcat[i + 2] = f2bf(v.z); wcat[i + 3] = f2bf(v.w);
}

// ---- concat bias ----
__global__ __launch_bounds__(256) void init_kernel(const float* __restrict__ bq,
                                                   const float* __restrict__ bk,
                                                   const float* __restrict__ bv,
                                                   float* __restrict__ bcat) {
  int k = blockIdx.x * 256 + threadIdx.x;
  if (k < 1536)
    bcat[k] = (k < 512) ? bq[k] : (k < 1024) ? bk[k - 512] : bv[k - 1024];
}

// ---- x[b][c][s] fp32 -> xs[b][s][c] bf16 (64x64 LDS tiles) ----
__global__ __launch_bounds__(256) void transpose_bf16_kernel(
    const float* __restrict__ x, const float* __restrict__ xt,
    unsigned short* __restrict__ xs, unsigned short* __restrict__ xts) {
  const int S = 2304, C = 768;
  const int z = blockIdx.z;
  const float* src = (z < 8) ? x : xt;
  unsigned short* dst = (z < 8) ? xs : xts;
  const int b = z & 7;
  src += (size_t)b * C * S;
  dst += (size_t)b * S * C;
  __shared__ float tile[64][65];
  const int s0 = blockIdx.x * 64, c0 = blockIdx.y * 64;
  const int ls = threadIdx.x & 63, lr = threadIdx.x >> 6;
#pragma unroll
  for (int i = 0; i < 16; ++i) {
    const int c = lr + i * 4;
    tile[c][ls] = src[(size_t)(c0 + c) * S + s0 + ls];
  }
  __syncthreads();
#pragma unroll
  for (int i = 0; i < 16; ++i) {
    const int s = lr + i * 4;
    dst[(size_t)(s0 + s) * C + c0 + ls] = f2bf(tile[ls][s]);
  }
}

// ================= 8-phase 256x256 GEMM-BT core (BK=64) =================
// LDS regions (16KB each, 128KB total): idx = dbuf*4 + side*2 + half.
// Swizzle (both sides): LDS 16B-slot sl at row r holds global slot sl^(r&7).

__device__ __forceinline__ void stage_half8(
    unsigned short* __restrict__ lds, const unsigned short* __restrict__ gb,
    int ldg, int tK, int side, int h, int tid, int swcol) {
  const int d = tK & 1;
  unsigned short* l0 = lds + (size_t)((d * 4 + side * 2 + h) * 8192);
  const unsigned short* g =
      gb + (size_t)(h * 128 + (tid >> 3)) * ldg + tK * 64 + swcol;
  GLOAD(g, l0 + (size_t)tid * 8);
  GLOAD(g + (size_t)64 * ldg, l0 + (size_t)(tid + 512) * 8);
}

#define RD(baseB, rh, cb)                                        \
  (*reinterpret_cast<const bf16x8*>(                             \
      reinterpret_cast<const char*>(lds) + (baseB) + (rh)*128 + (cb)))

#define PH_READ_A0(ABASE)                              \
  _Pragma("unroll") for (int mf = 0; mf < 4; ++mf) {   \
    a[mf][0] = RD(ABASE, mf * 16 + fr, cb0);           \
    a[mf][1] = RD(ABASE, mf * 16 + fr, cb1);           \
  }
#define PH_READ_A4(ABASE)                              \
  _Pragma("unroll") for (int mf = 0; mf < 4; ++mf) {   \
    a[mf][0] = RD(ABASE, 64 + mf * 16 + fr, cb0);      \
    a[mf][1] = RD(ABASE, 64 + mf * 16 + fr, cb1);      \
  }
#define PH_READ_B01(BBASE)                             \
  _Pragma("unroll") for (int nf = 0; nf < 2; ++nf) {   \
    b01[nf][0] = RD(BBASE, brh + nf * 16, cb0);        \
    b01[nf][1] = RD(BBASE, brh + nf * 16, cb1);        \
  }
#define PH_READ_B23(BBASE)                             \
  _Pragma("unroll") for (int nf = 0; nf < 2; ++nf) {   \
    b23[nf][0] = RD(BBASE, brh + 32 + nf * 16, cb0);   \
    b23[nf][1] = RD(BBASE, brh + 32 + nf * 16, cb1);   \
  }

#define BARRIER_MFMA(MB, NB, BF)                                      \
  __builtin_amdgcn_s_barrier();                                       \
  asm volatile("s_waitcnt lgkmcnt(0)" ::: "memory");                  \
  __builtin_amdgcn_sched_barrier(0);                                  \
  __builtin_amdgcn_s_setprio(1);                                      \
  _Pragma("unroll") for (int mf = 0; mf < 4; ++mf) {                  \
    acc[MB + mf][NB + 0] = __builtin_amdgcn_mfma_f32_16x16x32_bf16(   \
        a[mf][0], BF[0][0], acc[MB + mf][NB + 0], 0, 0, 0);           \
    acc[MB + mf][NB + 0] = __builtin_amdgcn_mfma_f32_16x16x32_bf16(   \
        a[mf][1], BF[0][1], acc[MB + mf][NB + 0], 0, 0, 0);           \
    acc[MB + mf][NB + 1] = __builtin_amdgcn_mfma_f32_16x16x32_bf16(   \
        a[mf][0], BF[1][0], acc[MB + mf][NB + 1], 0, 0, 0);           \
    acc[MB + mf][NB + 1] = __builtin_amdgcn_mfma_f32_16x16x32_bf16(   \
        a[mf][1], BF[1][1], acc[MB + mf][NB + 1], 0, 0, 0);           \
  }                                                                   \
  __builtin_amdgcn_s_setprio(0);                                      \
  __builtin_amdgcn_s_barrier();

template <int NT>
__device__ __forceinline__ void gemm8_core(
    const unsigned short* __restrict__ Ab, const unsigned short* __restrict__ Bb,
    int lda, int ldb, unsigned short* __restrict__ lds, f32x4 (&acc)[8][4]) {
  const int t = threadIdx.x;
  const int lane = t & 63, wid = t >> 6;
  const int wr = wid >> 2, wc = wid & 3;
  const int fr = lane & 15, fq = lane >> 4;
  const int swm = (fr & 7) << 4;
  const int cb0 = (fq * 16) ^ swm;
  const int cb1 = (64 + fq * 16) ^ swm;
  const int brh = (wc & 1) * 64 + fr;
  const int aB0 = (0 + wr) * 16384, aB1 = (4 + wr) * 16384;
  const int bB0 = (2 + (wc >> 1)) * 16384, bB1 = (6 + (wc >> 1)) * 16384;
  const int swcol = (((t & 7) ^ ((t >> 3) & 7))) * 8;

  bf16x8 a[4][2], b01[2][2], b23[2][2];

  // prologue: T0.B0,B1,A0,A1, T1.B0,B1 (12 loads); drain all but last 4
  stage_half8(lds, Bb, ldb, 0, 1, 0, t, swcol);
  stage_half8(lds, Bb, ldb, 0, 1, 1, t, swcol);
  stage_half8(lds, Ab, lda, 0, 0, 0, t, swcol);
  stage_half8(lds, Ab, lda, 0, 0, 1, t, swcol);
  stage_half8(lds, Bb, ldb, 1, 1, 0, t, swcol);
  stage_half8(lds, Bb, ldb, 1, 1, 1, t, swcol);
  asm volatile("s_waitcnt vmcnt(4)" ::: "memory");
  __builtin_amdgcn_s_barrier();

  const int NI = NT / 2;
#pragma unroll 1
  for (int i = 0; i < NI; ++i) {
    const bool more = (i + 1 < NI);
    const int tu1 = 2 * i + 1, tu2 = 2 * i + 2, tu3 = 2 * i + 3;
    // ---- P1: read B01(u)+A03(u); stage T(2i+1).A0 ----
    PH_READ_B01(bB0); PH_READ_A0(aB0);
    stage_half8(lds, Ab, lda, tu1, 0, 0, t, swcol);
    BARRIER_MFMA(0, 0, b01);
    // ---- P2: read B23(u); stage T(2i+1).A1 ----
    PH_READ_B23(bB0);
    stage_half8(lds, Ab, lda, tu1, 0, 1, t, swcol);
    BARRIER_MFMA(0, 2, b23);
    // ---- P3: read A47(u); stage T(2i+2).B0 ----
    PH_READ_A4(aB0);
    if (more) stage_half8(lds, Bb, ldb, tu2, 1, 0, t, swcol);
    BARRIER_MFMA(4, 2, b23);
    // ---- P4: stage T(2i+2).B1; gate tile 2i+1 ----
    if (more) {
      stage_half8(lds, Bb, ldb, tu2, 1, 1, t, swcol);
      asm volatile("s_waitcnt vmcnt(4)" ::: "memory");
    } else {
      asm volatile("s_waitcnt vmcnt(0)" ::: "memory");
    }
    BARRIER_MFMA(4, 0, b01);
    // ---- P5: read B01(v)+A03(v); stage T(2i+2).A0 ----
    PH_READ_B01(bB1); PH_READ_A0(aB1);
    if (more) stage_half8(lds, Ab, lda, tu2, 0, 0, t, swcol);
    BARRIER_MFMA(0, 0, b01);
    // ---- P6: read B23(v); stage T(2i+2).A1 ----
    PH_READ_B23(bB1);
    if (more) stage_half8(lds, Ab, lda, tu2, 0, 1, t, swcol);
    BARRIER_MFMA(0, 2, b23);
    // ---- P7: read A47(v); stage T(2i+3).B0 ----
    PH_READ_A4(aB1);
    if (more) stage_half8(lds, Bb, ldb, tu3, 1, 0, t, swcol);
    BARRIER_MFMA(4, 2, b23);
    // ---- P8: stage T(2i+3).B1; gate tile 2i+2 ----
    if (more) {
      stage_half8(lds, Bb, ldb, tu3, 1, 1, t, swcol);
      asm volatile("s_waitcnt vmcnt(4)" ::: "memory");
    }
    BARRIER_MFMA(4, 0, b01);
  }
}

// ---- fused QKV projection, 8-phase 256^2, K=768 (NT=12) ----
__global__ __launch_bounds__(512) void qkv8_kernel(
    const unsigned short* __restrict__ xs, const unsigned short* __restrict__ xts,
    const unsigned short* __restrict__ wcat, const float* __restrict__ bcat,
    unsigned short* __restrict__ Q, unsigned short* __restrict__ K,
    unsigned short* __restrict__ Vt) {
  extern __shared__ unsigned short lds[];
  const int lin = blockIdx.x + 6 * (blockIdx.y + 9 * blockIdx.z);
  const int b = lin & 7, idx = lin >> 3;       // idx in [0,54)
  const int byp = idx / 6, bxp = idx - byp * 6;
  const int m0 = byp * 256, n0 = bxp * 256;
  const int seg = n0 >> 9;
  const unsigned short* Ab =
      ((seg == 0) ? xs : xts) + (size_t)b * 2304 * 768 + (size_t)m0 * 768;
  const unsigned short* Bb = wcat + (size_t)n0 * 768;
  f32x4 acc[8][4] = {};
  gemm8_core<12>(Ab, Bb, 768, 768, lds, acc);

  const int t = threadIdx.x;
  const int lane = t & 63, wid = t >> 6;
  const int wr = wid >> 2, wc = wid & 3;
  const int fr = lane & 15, fq = lane >> 4;
  if (seg < 2) {
    unsigned short* Cp = ((seg == 0) ? Q : K) + (size_t)b * 2304 * 512;
#pragma unroll
    for (int nf = 0; nf < 4; ++nf) {
      const int ng = n0 + wc * 64 + nf * 16 + fr;
      const float bj = bcat[ng];
      const int col = ng - seg * 512;
#pragma unroll
      for (int mf = 0; mf < 8; ++mf) {
        const int rbase = m0 + wr * 128 + mf * 16 + fq * 4;
#pragma unroll
        for (int r = 0; r < 4; ++r)
          Cp[(size_t)(rbase + r) * 512 + col] = f2bf(acc[mf][nf][r] + bj);
      }
    }
  } else {
    unsigned short* Cp = Vt + (size_t)b * 512 * 2304;
#pragma unroll
    for (int nf = 0; nf < 4; ++nf) {
      const int ng = n0 + wc * 64 + nf * 16 + fr;
      const float bj = bcat[ng];
      const int d = ng - 1024;
#pragma unroll
      for (int mf = 0; mf < 8; ++mf) {
        const int tb = m0 + wr * 128 + mf * 16 + fq * 4;
        ushort4 pk;
        pk.x = f2bf(acc[mf][nf][0] + bj);
        pk.y = f2bf(acc[mf][nf][1] + bj);
        pk.z = f2bf(acc[mf][nf][2] + bj);
        pk.w = f2bf(acc[mf][nf][3] + bj);
        *reinterpret_cast<ushort4*>(&Cp[(size_t)d * 2304 + tb]) = pk;
      }
    }
  }
}

// ---- scores, 8-phase 256^2, K=512 (NT=8) ----
// Epilogue: exp+store; per-row partial over this block's 256-col slab
// reduced via fr-shfl then cross-wave combine in LDS (dead after K-loop),
// one plain store per row into psum[b][row][bxp]. No atomics.
__global__ __launch_bounds__(512) void scores8_kernel(
    const unsigned short* __restrict__ Qm, const unsigned short* __restrict__ Km,
    unsigned short* __restrict__ P, float* __restrict__ psum) {
  extern __shared__ unsigned short lds[];
  const int lin = blockIdx.x + 9 * (blockIdx.y + 9 * blockIdx.z);
  const int b = lin & 7, idx = lin >> 3;       // idx in [0,81)
  const int bxp = idx / 9, byp = idx - bxp * 9;
  const int m0 = byp * 256, n0 = bxp * 256;
  const unsigned short* Ab = Qm + (size_t)b * 2304 * 512 + (size_t)m0 * 512;
  const unsigned short* Bb = Km + (size_t)b * 2304 * 512 + (size_t)n0 * 512;
  f32x4 acc[8][4] = {};
  gemm8_core<8>(Ab, Bb, 512, 512, lds, acc);

  const int t = threadIdx.x;
  const int lane = t & 63, wid = t >> 6;
  const int wr = wid >> 2, wc = wid & 3;
  const int fr = lane & 15, fq = lane >> 4;
  unsigned short* Pp = P + (size_t)b * 2304 * 2304;
  const float SC = 0.044194173824159216f;
  float* lf = (float*)lds;  // [256 rows][4 wc-slabs], 4KB (post-loop reuse)
#pragma unroll
  for (int mf = 0; mf < 8; ++mf) {
    float rs[4] = {0.f, 0.f, 0.f, 0.f};
    const int rl = wr * 128 + mf * 16 + fq * 4;  // local row base
    const int rbase = m0 + rl;
#pragma unroll
    for (int nf = 0; nf < 4; ++nf) {
      const int col = n0 + wc * 64 + nf * 16 + fr;
#pragma unroll
      for (int r = 0; r < 4; ++r) {
        const float e = __expf(acc[mf][nf][r] * SC - 4.0f);
        rs[r] += e;
        Pp[(size_t)(rbase + r) * 2304 + col] = f2bf(e);
      }
    }
#pragma unroll
    for (int r = 0; r < 4; ++r) {
      float s = rs[r];
#pragma unroll
      for (int o = 8; o >= 1; o >>= 1) s += __shfl_xor(s, o, 16);
      if (fr == 0) lf[(rl + r) * 4 + wc] = s;
    }
  }
  __syncthreads();
  if (t < 256) {
    const float tot = lf[t * 4 + 0] + lf[t * 4 + 1] + lf[t * 4 + 2] + lf[t * 4 + 3];
    psum[((size_t)b * 2304 + m0 + t) * 9 + bxp] = tot;
  }
}

// ---- combine: denom[g] = sum of 9 psum partials ----
__global__ __launch_bounds__(256) void combine_kernel(
    const float* __restrict__ psum, float* __restrict__ denom) {
  const int g = blockIdx.x * 256 + threadIdx.x;  // < 18432
  const float* p = psum + (size_t)g * 9;
  denom[g] = ((p[0] + p[1]) + (p[2] + p[3])) +
             ((p[4] + p[5]) + (p[6] + p[7])) + p[8];
}

// ---- PV, 8-phase 256^2, K=2304 (NT=36): out = (P @ Vt^T)/denom, fp32 ----
__global__ __launch_bounds__(512) void pv8_kernel(
    const unsigned short* __restrict__ P, const unsigned short* __restrict__ Vt,
    const float* __restrict__ denom, float* __restrict__ Out) {
  extern __shared__ unsigned short lds[];
  const int lin = blockIdx.x + 2 * (blockIdx.y + 9 * blockIdx.z);
  const int b = lin & 7, idx = lin >> 3;       // idx in [0,18)
  const int byp = idx >> 1, bxp = idx & 1;
  const int m0 = byp * 256, n0 = bxp * 256;
  const unsigned short* Ab = P + (size_t)b * 2304 * 2304 + (size_t)m0 * 2304;
  const unsigned short* Bb = Vt + (size_t)b * 512 * 2304 + (size_t)n0 * 2304;
  f32x4 acc[8][4] = {};
  gemm8_core<36>(Ab, Bb, 2304, 2304, lds, acc);

  const int t = threadIdx.x;
  const int lane = t & 63, wid = t >> 6;
  const int wr = wid >> 2, wc = wid & 3;
  const int fr = lane & 15, fq = lane >> 4;
  float* Cp = Out + (size_t)b * 2304 * 512;
  const float* dn = denom + (size_t)b * 2304;
#pragma unroll
  for (int mf = 0; mf < 8; ++mf) {
    const int rbase = m0 + wr * 128 + mf * 16 + fq * 4;
#pragma unroll
    for (int r = 0; r < 4; ++r) {
      const float inv = 1.0f / dn[rbase + r];
#pragma unroll
      for (int nf = 0; nf < 4; ++nf) {
        const int col = n0 + wc * 64 + nf * 16 + fr;
        Cp[(size_t)(rbase + r) * 512 + col] = acc[mf][nf][r] * inv;
      }
    }
  }
}

extern "C" void kernel_launch(void* const* d_in, const int* in_sizes, int n_in,
                              void* d_out, int out_size, void* d_ws, size_t ws_size,
                              hipStream_t stream) {
  const float* x  = (const float*)d_in[0];
  const float* xt = (const float*)d_in[1];
  const float* wq = (const float*)d_in[2];
  const float* bq = (const float*)d_in[3];
  const float* wk = (const float*)d_in[4];
  const float* bk = (const float*)d_in[5];
  const float* wv = (const float*)d_in[6];
  const float* bv = (const float*)d_in[7];
  float* out = (float*)d_out;
  unsigned short* ws = (unsigned short*)d_ws;

  unsigned short* Q    = ws;
  unsigned short* Kb   = ws + 9437184;
  unsigned short* Vt   = ws + 18874368;
  unsigned short* P    = ws + 28311552;   // 85MB region
  unsigned short* xs   = ws + 28311552;   // aliases P (dead before P written)
  unsigned short* xts  = ws + 42467328;
  unsigned short* wcat = ws + 56623104;   // wq|wk|wv contiguous (1536x768)
  float* bcat  = (float*)(ws + 57802752); // 1536 f32 (inside P region, dead early)
  float* denom = (float*)(ws + 70778880); // 18432 f32, after P
  float* psum  = (float*)(ws + 70815744); // 8*2304*9 = 165888 f32

  static int attr_set = 0;
  if (!attr_set) {
    hipFuncSetAttribute((const void*)qkv8_kernel,
                        hipFuncAttributeMaxDynamicSharedMemorySize, 131072);
    hipFuncSetAttribute((const void*)scores8_kernel,
                        hipFuncAttributeMaxDynamicSharedMemorySize, 131072);
    hipFuncSetAttribute((const void*)pv8_kernel,
                        hipFuncAttributeMaxDynamicSharedMemorySize, 131072);
    attr_set = 1;
  }

  convw3_kernel<<<1152, 256, 0, stream>>>(wq, wk, wv, wcat);
  init_kernel<<<6, 256, 0, stream>>>(bq, bk, bv, bcat);
  transpose_bf16_kernel<<<dim3(36, 12, 16), 256, 0, stream>>>(x, xt, xs, xts);

  // fused Q|K|V projection (8-phase 256^2)
  qkv8_kernel<<<dim3(6, 9, 8), 512, 131072, stream>>>(xs, xts, wcat, bcat, Q, Kb, Vt);

  // P = exp(Q K^T / sqrt(D) - 4); psum[b][row][n_idx] = slab rowsum
  scores8_kernel<<<dim3(9, 9, 8), 512, 131072, stream>>>(Q, Kb, P, psum);

  // denom[row] = sum of 9 slab partials
  combine_kernel<<<72, 256, 0, stream>>>(psum, denom);

  // out = (P @ V) / denom[row]
  pv8_kernel<<<dim3(2, 9, 8), 512, 131072, stream>>>(P, Vt, denom, out);
}

// Round 15
// 216.682 us; speedup vs baseline: 1.1818x; 1.0143x over previous
//
#include <hip/hip_runtime.h>
#include <stdint.h>

// CrossAttentionHead: B=8, C=768, S=T=2304, D=512.
// transpose/cvt (vectorized) -> qkv8 (256^2 8-phase BK=64, counted vmcnt,
// T2 swizzle) -> scores8 (same core; exp+store + LDS psum partials) ->
// combine -> pv8 (1/denom fp32 epilogue). Batch->XCD swizzle everywhere.
//
// Round-15: transpose rewritten with float4 loads + 16B ushort8 stores
// (was 4B loads / 2B stores); convw+init merged into one launch.
//
// Workspace (ushort elems):
//   Q[0,..) K[9437184,..) Vt[18874368,..)  (each 9,437,184)
//   P@28311552 (42,467,328 elems, 85MB); aliased inside P (dead before P):
//   xs@28311552, xts@42467328, wcat@56623104 (wq|wk|wv, 1536x768),
//   bcat(f32)@ushort 57802752; denom(f32,18432)@ushort 70778880;
//   psum(f32, 8*2304*9=165888)@ushort 70815744 (end 142,295,040 B).

typedef __bf16 bf16x8 __attribute__((ext_vector_type(8)));
typedef float f32x4 __attribute__((ext_vector_type(4)));

__device__ __forceinline__ unsigned short f2bf(float f) {
  union { float f; unsigned int u; } c; c.f = f;
  return (unsigned short)((c.u + 0x7fffu + ((c.u >> 16) & 1u)) >> 16); // RNE
}

#define GLOAD(gp, lp)                                                          \
  __builtin_amdgcn_global_load_lds(                                            \
      (const __attribute__((address_space(1))) void*)(gp),                     \
      (__attribute__((address_space(3))) void*)(lp), 16, 0, 0)

// ---- weights fp32 -> bf16 into contiguous wcat + bias concat (merged) ----
__global__ __launch_bounds__(256) void convw_init_kernel(
    const float* __restrict__ wq, const float* __restrict__ wk,
    const float* __restrict__ wv, const float* __restrict__ bq,
    const float* __restrict__ bk, const float* __restrict__ bv,
    unsigned short* __restrict__ wcat, float* __restrict__ bcat) {
  if (blockIdx.x < 1152) {
    int i = (blockIdx.x * 256 + threadIdx.x) * 4;
    const float* src = (i < 393216) ? wq : (i < 786432) ? wk : wv;
    const int off = (i < 393216) ? 0 : (i < 786432) ? 393216 : 786432;
    const float4 v = *reinterpret_cast<const float4*>(src + (i - off));
    wcat[i + 0] = f2bf(v.x); wcat[i + 1] = f2bf(v.y);
    wcat[i + 2] = f2bf(v.z); wcat[i + 3] = f2bf(v.w);
  } else {
    int k = (blockIdx.x - 1152) * 256 + threadIdx.x;
    if (k < 1536)
      bcat[k] = (k < 512) ? bq[k] : (k < 1024) ? bk[k - 512] : bv[k - 1024];
  }
}

// ---- x[b][c][s] fp32 -> xs[b][s][c] bf16; float4 loads, ushort8 stores ----
__global__ __launch_bounds__(256) void transpose_bf16_kernel(
    const float* __restrict__ x, const float* __restrict__ xt,
    unsigned short* __restrict__ xs, unsigned short* __restrict__ xts) {
  const int S = 2304, C = 768;
  const int z = blockIdx.z;
  const float* src = (z < 8) ? x : xt;
  unsigned short* dst = (z < 8) ? xs : xts;
  const int b = z & 7;
  src += (size_t)b * C * S;
  dst += (size_t)b * S * C;
  __shared__ float tile[64][65];  // [c][s], pad breaks pow2 strides
  const int s0 = blockIdx.x * 64, c0 = blockIdx.y * 64;
  const int t = threadIdx.x;
  const int sl4 = (t & 15) * 4, cl = t >> 4;
#pragma unroll
  for (int i = 0; i < 4; ++i) {
    const int c = cl + i * 16;
    *reinterpret_cast<float4*>(&tile[c][sl4]) =
        *reinterpret_cast<const float4*>(&src[(size_t)(c0 + c) * S + s0 + sl4]);
  }
  __syncthreads();
#pragma unroll
  for (int i = 0; i < 2; ++i) {
    const int idx = t + i * 256;
    const int s = idx >> 3, c8 = (idx & 7) * 8;
    unsigned int pk[4];
#pragma unroll
    for (int j = 0; j < 4; ++j) {
      const unsigned int lo = f2bf(tile[c8 + 2 * j][s]);
      const unsigned int hi = f2bf(tile[c8 + 2 * j + 1][s]);
      pk[j] = lo | (hi << 16);
    }
    *reinterpret_cast<uint4*>(&dst[(size_t)(s0 + s) * C + c0 + c8]) =
        *reinterpret_cast<uint4*>(pk);
  }
}

// ================= 8-phase 256x256 GEMM-BT core (BK=64) =================
// LDS regions (16KB each, 128KB total): idx = dbuf*4 + side*2 + half.
// Swizzle (both sides): LDS 16B-slot sl at row r holds global slot sl^(r&7).

__device__ __forceinline__ void stage_half8(
    unsigned short* __restrict__ lds, const unsigned short* __restrict__ gb,
    int ldg, int tK, int side, int h, int tid, int swcol) {
  const int d = tK & 1;
  unsigned short* l0 = lds + (size_t)((d * 4 + side * 2 + h) * 8192);
  const unsigned short* g =
      gb + (size_t)(h * 128 + (tid >> 3)) * ldg + tK * 64 + swcol;
  GLOAD(g, l0 + (size_t)tid * 8);
  GLOAD(g + (size_t)64 * ldg, l0 + (size_t)(tid + 512) * 8);
}

#define RD(baseB, rh, cb)                                        \
  (*reinterpret_cast<const bf16x8*>(                             \
      reinterpret_cast<const char*>(lds) + (baseB) + (rh)*128 + (cb)))

#define PH_READ_A0(ABASE)                              \
  _Pragma("unroll") for (int mf = 0; mf < 4; ++mf) {   \
    a[mf][0] = RD(ABASE, mf * 16 + fr, cb0);           \
    a[mf][1] = RD(ABASE, mf * 16 + fr, cb1);           \
  }
#define PH_READ_A4(ABASE)                              \
  _Pragma("unroll") for (int mf = 0; mf < 4; ++mf) {   \
    a[mf][0] = RD(ABASE, 64 + mf * 16 + fr, cb0);      \
    a[mf][1] = RD(ABASE, 64 + mf * 16 + fr, cb1);      \
  }
#define PH_READ_B01(BBASE)                             \
  _Pragma("unroll") for (int nf = 0; nf < 2; ++nf) {   \
    b01[nf][0] = RD(BBASE, brh + nf * 16, cb0);        \
    b01[nf][1] = RD(BBASE, brh + nf * 16, cb1);        \
  }
#define PH_READ_B23(BBASE)                             \
  _Pragma("unroll") for (int nf = 0; nf < 2; ++nf) {   \
    b23[nf][0] = RD(BBASE, brh + 32 + nf * 16, cb0);   \
    b23[nf][1] = RD(BBASE, brh + 32 + nf * 16, cb1);   \
  }

#define BARRIER_MFMA(MB, NB, BF)                                      \
  __builtin_amdgcn_s_barrier();                                       \
  asm volatile("s_waitcnt lgkmcnt(0)" ::: "memory");                  \
  __builtin_amdgcn_sched_barrier(0);                                  \
  __builtin_amdgcn_s_setprio(1);                                      \
  _Pragma("unroll") for (int mf = 0; mf < 4; ++mf) {                  \
    acc[MB + mf][NB + 0] = __builtin_amdgcn_mfma_f32_16x16x32_bf16(   \
        a[mf][0], BF[0][0], acc[MB + mf][NB + 0], 0, 0, 0);           \
    acc[MB + mf][NB + 0] = __builtin_amdgcn_mfma_f32_16x16x32_bf16(   \
        a[mf][1], BF[0][1], acc[MB + mf][NB + 0], 0, 0, 0);           \
    acc[MB + mf][NB + 1] = __builtin_amdgcn_mfma_f32_16x16x32_bf16(   \
        a[mf][0], BF[1][0], acc[MB + mf][NB + 1], 0, 0, 0);           \
    acc[MB + mf][NB + 1] = __builtin_amdgcn_mfma_f32_16x16x32_bf16(   \
        a[mf][1], BF[1][1], acc[MB + mf][NB + 1], 0, 0, 0);           \
  }                                                                   \
  __builtin_amdgcn_s_setprio(0);                                      \
  __builtin_amdgcn_s_barrier();

template <int NT>
__device__ __forceinline__ void gemm8_core(
    const unsigned short* __restrict__ Ab, const unsigned short* __restrict__ Bb,
    int lda, int ldb, unsigned short* __restrict__ lds, f32x4 (&acc)[8][4]) {
  const int t = threadIdx.x;
  const int lane = t & 63, wid = t >> 6;
  const int wr = wid >> 2, wc = wid & 3;
  const int fr = lane & 15, fq = lane >> 4;
  const int swm = (fr & 7) << 4;
  const int cb0 = (fq * 16) ^ swm;
  const int cb1 = (64 + fq * 16) ^ swm;
  const int brh = (wc & 1) * 64 + fr;
  const int aB0 = (0 + wr) * 16384, aB1 = (4 + wr) * 16384;
  const int bB0 = (2 + (wc >> 1)) * 16384, bB1 = (6 + (wc >> 1)) * 16384;
  const int swcol = (((t & 7) ^ ((t >> 3) & 7))) * 8;

  bf16x8 a[4][2], b01[2][2], b23[2][2];

  // prologue: T0.B0,B1,A0,A1, T1.B0,B1 (12 loads); drain all but last 4
  stage_half8(lds, Bb, ldb, 0, 1, 0, t, swcol);
  stage_half8(lds, Bb, ldb, 0, 1, 1, t, swcol);
  stage_half8(lds, Ab, lda, 0, 0, 0, t, swcol);
  stage_half8(lds, Ab, lda, 0, 0, 1, t, swcol);
  stage_half8(lds, Bb, ldb, 1, 1, 0, t, swcol);
  stage_half8(lds, Bb, ldb, 1, 1, 1, t, swcol);
  asm volatile("s_waitcnt vmcnt(4)" ::: "memory");
  __builtin_amdgcn_s_barrier();

  const int NI = NT / 2;
#pragma unroll 1
  for (int i = 0; i < NI; ++i) {
    const bool more = (i + 1 < NI);
    const int tu1 = 2 * i + 1, tu2 = 2 * i + 2, tu3 = 2 * i + 3;
    // ---- P1: read B01(u)+A03(u); stage T(2i+1).A0 ----
    PH_READ_B01(bB0); PH_READ_A0(aB0);
    stage_half8(lds, Ab, lda, tu1, 0, 0, t, swcol);
    BARRIER_MFMA(0, 0, b01);
    // ---- P2: read B23(u); stage T(2i+1).A1 ----
    PH_READ_B23(bB0);
    stage_half8(lds, Ab, lda, tu1, 0, 1, t, swcol);
    BARRIER_MFMA(0, 2, b23);
    // ---- P3: read A47(u); stage T(2i+2).B0 ----
    PH_READ_A4(aB0);
    if (more) stage_half8(lds, Bb, ldb, tu2, 1, 0, t, swcol);
    BARRIER_MFMA(4, 2, b23);
    // ---- P4: stage T(2i+2).B1; gate tile 2i+1 ----
    if (more) {
      stage_half8(lds, Bb, ldb, tu2, 1, 1, t, swcol);
      asm volatile("s_waitcnt vmcnt(4)" ::: "memory");
    } else {
      asm volatile("s_waitcnt vmcnt(0)" ::: "memory");
    }
    BARRIER_MFMA(4, 0, b01);
    // ---- P5: read B01(v)+A03(v); stage T(2i+2).A0 ----
    PH_READ_B01(bB1); PH_READ_A0(aB1);
    if (more) stage_half8(lds, Ab, lda, tu2, 0, 0, t, swcol);
    BARRIER_MFMA(0, 0, b01);
    // ---- P6: read B23(v); stage T(2i+2).A1 ----
    PH_READ_B23(bB1);
    if (more) stage_half8(lds, Ab, lda, tu2, 0, 1, t, swcol);
    BARRIER_MFMA(0, 2, b23);
    // ---- P7: read A47(v); stage T(2i+3).B0 ----
    PH_READ_A4(aB1);
    if (more) stage_half8(lds, Bb, ldb, tu3, 1, 0, t, swcol);
    BARRIER_MFMA(4, 2, b23);
    // ---- P8: stage T(2i+3).B1; gate tile 2i+2 ----
    if (more) {
      stage_half8(lds, Bb, ldb, tu3, 1, 1, t, swcol);
      asm volatile("s_waitcnt vmcnt(4)" ::: "memory");
    }
    BARRIER_MFMA(4, 0, b01);
  }
}

// ---- fused QKV projection, 8-phase 256^2, K=768 (NT=12) ----
__global__ __launch_bounds__(512) void qkv8_kernel(
    const unsigned short* __restrict__ xs, const unsigned short* __restrict__ xts,
    const unsigned short* __restrict__ wcat, const float* __restrict__ bcat,
    unsigned short* __restrict__ Q, unsigned short* __restrict__ K,
    unsigned short* __restrict__ Vt) {
  extern __shared__ unsigned short lds[];
  const int lin = blockIdx.x + 6 * (blockIdx.y + 9 * blockIdx.z);
  const int b = lin & 7, idx = lin >> 3;       // idx in [0,54)
  const int byp = idx / 6, bxp = idx - byp * 6;
  const int m0 = byp * 256, n0 = bxp * 256;
  const int seg = n0 >> 9;
  const unsigned short* Ab =
      ((seg == 0) ? xs : xts) + (size_t)b * 2304 * 768 + (size_t)m0 * 768;
  const unsigned short* Bb = wcat + (size_t)n0 * 768;
  f32x4 acc[8][4] = {};
  gemm8_core<12>(Ab, Bb, 768, 768, lds, acc);

  const int t = threadIdx.x;
  const int lane = t & 63, wid = t >> 6;
  const int wr = wid >> 2, wc = wid & 3;
  const int fr = lane & 15, fq = lane >> 4;
  if (seg < 2) {
    unsigned short* Cp = ((seg == 0) ? Q : K) + (size_t)b * 2304 * 512;
#pragma unroll
    for (int nf = 0; nf < 4; ++nf) {
      const int ng = n0 + wc * 64 + nf * 16 + fr;
      const float bj = bcat[ng];
      const int col = ng - seg * 512;
#pragma unroll
      for (int mf = 0; mf < 8; ++mf) {
        const int rbase = m0 + wr * 128 + mf * 16 + fq * 4;
#pragma unroll
        for (int r = 0; r < 4; ++r)
          Cp[(size_t)(rbase + r) * 512 + col] = f2bf(acc[mf][nf][r] + bj);
      }
    }
  } else {
    unsigned short* Cp = Vt + (size_t)b * 512 * 2304;
#pragma unroll
    for (int nf = 0; nf < 4; ++nf) {
      const int ng = n0 + wc * 64 + nf * 16 + fr;
      const float bj = bcat[ng];
      const int d = ng - 1024;
#pragma unroll
      for (int mf = 0; mf < 8; ++mf) {
        const int tb = m0 + wr * 128 + mf * 16 + fq * 4;
        ushort4 pk;
        pk.x = f2bf(acc[mf][nf][0] + bj);
        pk.y = f2bf(acc[mf][nf][1] + bj);
        pk.z = f2bf(acc[mf][nf][2] + bj);
        pk.w = f2bf(acc[mf][nf][3] + bj);
        *reinterpret_cast<ushort4*>(&Cp[(size_t)d * 2304 + tb]) = pk;
      }
    }
  }
}

// ---- scores, 8-phase 256^2, K=512 (NT=8) ----
// Epilogue: exp+store; per-row slab partial via fr-shfl + LDS combine,
// one plain store per row into psum[b][row][bxp]. No atomics.
__global__ __launch_bounds__(512) void scores8_kernel(
    const unsigned short* __restrict__ Qm, const unsigned short* __restrict__ Km,
    unsigned short* __restrict__ P, float* __restrict__ psum) {
  extern __shared__ unsigned short lds[];
  const int lin = blockIdx.x + 9 * (blockIdx.y + 9 * blockIdx.z);
  const int b = lin & 7, idx = lin >> 3;       // idx in [0,81)
  const int bxp = idx / 9, byp = idx - bxp * 9;
  const int m0 = byp * 256, n0 = bxp * 256;
  const unsigned short* Ab = Qm + (size_t)b * 2304 * 512 + (size_t)m0 * 512;
  const unsigned short* Bb = Km + (size_t)b * 2304 * 512 + (size_t)n0 * 512;
  f32x4 acc[8][4] = {};
  gemm8_core<8>(Ab, Bb, 512, 512, lds, acc);

  const int t = threadIdx.x;
  const int lane = t & 63, wid = t >> 6;
  const int wr = wid >> 2, wc = wid & 3;
  const int fr = lane & 15, fq = lane >> 4;
  unsigned short* Pp = P + (size_t)b * 2304 * 2304;
  const float SC = 0.044194173824159216f;
  float* lf = (float*)lds;  // [256 rows][4 wc-slabs], post-loop reuse
#pragma unroll
  for (int mf = 0; mf < 8; ++mf) {
    float rs[4] = {0.f, 0.f, 0.f, 0.f};
    const int rl = wr * 128 + mf * 16 + fq * 4;
    const int rbase = m0 + rl;
#pragma unroll
    for (int nf = 0; nf < 4; ++nf) {
      const int col = n0 + wc * 64 + nf * 16 + fr;
#pragma unroll
      for (int r = 0; r < 4; ++r) {
        const float e = __expf(acc[mf][nf][r] * SC - 4.0f);
        rs[r] += e;
        Pp[(size_t)(rbase + r) * 2304 + col] = f2bf(e);
      }
    }
#pragma unroll
    for (int r = 0; r < 4; ++r) {
      float s = rs[r];
#pragma unroll
      for (int o = 8; o >= 1; o >>= 1) s += __shfl_xor(s, o, 16);
      if (fr == 0) lf[(rl + r) * 4 + wc] = s;
    }
  }
  __syncthreads();
  if (t < 256) {
    const float tot = lf[t * 4 + 0] + lf[t * 4 + 1] + lf[t * 4 + 2] + lf[t * 4 + 3];
    psum[((size_t)b * 2304 + m0 + t) * 9 + bxp] = tot;
  }
}

// ---- combine: denom[g] = sum of 9 psum partials ----
__global__ __launch_bounds__(256) void combine_kernel(
    const float* __restrict__ psum, float* __restrict__ denom) {
  const int g = blockIdx.x * 256 + threadIdx.x;  // < 18432
  const float* p = psum + (size_t)g * 9;
  denom[g] = ((p[0] + p[1]) + (p[2] + p[3])) +
             ((p[4] + p[5]) + (p[6] + p[7])) + p[8];
}

// ---- PV, 8-phase 256^2, K=2304 (NT=36): out = (P @ Vt^T)/denom, fp32 ----
__global__ __launch_bounds__(512) void pv8_kernel(
    const unsigned short* __restrict__ P, const unsigned short* __restrict__ Vt,
    const float* __restrict__ denom, float* __restrict__ Out) {
  extern __shared__ unsigned short lds[];
  const int lin = blockIdx.x + 2 * (blockIdx.y + 9 * blockIdx.z);
  const int b = lin & 7, idx = lin >> 3;       // idx in [0,18)
  const int byp = idx >> 1, bxp = idx & 1;
  const int m0 = byp * 256, n0 = bxp * 256;
  const unsigned short* Ab = P + (size_t)b * 2304 * 2304 + (size_t)m0 * 2304;
  const unsigned short* Bb = Vt + (size_t)b * 512 * 2304 + (size_t)n0 * 2304;
  f32x4 acc[8][4] = {};
  gemm8_core<36>(Ab, Bb, 2304, 2304, lds, acc);

  const int t = threadIdx.x;
  const int lane = t & 63, wid = t >> 6;
  const int wr = wid >> 2, wc = wid & 3;
  const int fr = lane & 15, fq = lane >> 4;
  float* Cp = Out + (size_t)b * 2304 * 512;
  const float* dn = denom + (size_t)b * 2304;
#pragma unroll
  for (int mf = 0; mf < 8; ++mf) {
    const int rbase = m0 + wr * 128 + mf * 16 + fq * 4;
#pragma unroll
    for (int r = 0; r < 4; ++r) {
      const float inv = 1.0f / dn[rbase + r];
#pragma unroll
      for (int nf = 0; nf < 4; ++nf) {
        const int col = n0 + wc * 64 + nf * 16 + fr;
        Cp[(size_t)(rbase + r) * 512 + col] = acc[mf][nf][r] * inv;
      }
    }
  }
}

extern "C" void kernel_launch(void* const* d_in, const int* in_sizes, int n_in,
                              void* d_out, int out_size, void* d_ws, size_t ws_size,
                              hipStream_t stream) {
  const float* x  = (const float*)d_in[0];
  const float* xt = (const float*)d_in[1];
  const float* wq = (const float*)d_in[2];
  const float* bq = (const float*)d_in[3];
  const float* wk = (const float*)d_in[4];
  const float* bk = (const float*)d_in[5];
  const float* wv = (const float*)d_in[6];
  const float* bv = (const float*)d_in[7];
  float* out = (float*)d_out;
  unsigned short* ws = (unsigned short*)d_ws;

  unsigned short* Q    = ws;
  unsigned short* Kb   = ws + 9437184;
  unsigned short* Vt   = ws + 18874368;
  unsigned short* P    = ws + 28311552;   // 85MB region
  unsigned short* xs   = ws + 28311552;   // aliases P (dead before P written)
  unsigned short* xts  = ws + 42467328;
  unsigned short* wcat = ws + 56623104;   // wq|wk|wv contiguous (1536x768)
  float* bcat  = (float*)(ws + 57802752); // 1536 f32 (inside P region, dead early)
  float* denom = (float*)(ws + 70778880); // 18432 f32, after P
  float* psum  = (float*)(ws + 70815744); // 8*2304*9 = 165888 f32

  static int attr_set = 0;
  if (!attr_set) {
    hipFuncSetAttribute((const void*)qkv8_kernel,
                        hipFuncAttributeMaxDynamicSharedMemorySize, 131072);
    hipFuncSetAttribute((const void*)scores8_kernel,
                        hipFuncAttributeMaxDynamicSharedMemorySize, 131072);
    hipFuncSetAttribute((const void*)pv8_kernel,
                        hipFuncAttributeMaxDynamicSharedMemorySize, 131072);
    attr_set = 1;
  }

  convw_init_kernel<<<1158, 256, 0, stream>>>(wq, wk, wv, bq, bk, bv, wcat, bcat);
  transpose_bf16_kernel<<<dim3(36, 12, 16), 256, 0, stream>>>(x, xt, xs, xts);

  // fused Q|K|V projection (8-phase 256^2)
  qkv8_kernel<<<dim3(6, 9, 8), 512, 131072, stream>>>(xs, xts, wcat, bcat, Q, Kb, Vt);

  // P = exp(Q K^T / sqrt(D) - 4); psum[b][row][n_idx] = slab rowsum
  scores8_kernel<<<dim3(9, 9, 8), 512, 131072, stream>>>(Q, Kb, P, psum);

  // denom[row] = sum of 9 slab partials
  combine_kernel<<<72, 256, 0, stream>>>(psum, denom);

  // out = (P @ V) / denom[row]
  pv8_kernel<<<dim3(2, 9, 8), 512, 131072, stream>>>(P, Vt, denom, out);
}